// Round 5
// baseline (899.148 us; speedup 1.0000x reference)
//
#include <hip/hip_runtime.h>
#include <math.h>

// ============================================================================
// INSTRUMENTATION BUILD (round 5): idempotent hot kernels loop their bodies
// x8 in-kernel so their dispatches rise above the 44 µs harness fills and
// become visible in the top-5 profile. Correctness preserved (repeat =
// rewrite identical values). dur_us is expected to inflate ~4-6x this round.
// De-amplify next round by setting IREPS to 1.
// ============================================================================
#define IREPS 8

#define NNODES 50000
#define NEDGES 800000
#define NGRAPHS 500
#define NEG_SLOPE 0.2f
#define BN_EPS 1e-5f
#define NRANGE 196            // ceil(50000/256) node ranges of 256
#define RH_EPB 2048           // edges per block in range hist/reorder (391 blocks)
#define RH_NB ((NEDGES + RH_EPB - 1) / RH_EPB)
#define MAXRE 5120            // LDS stage capacity per range
#define BN_NB 400
#define BN_RPB 125

typedef unsigned int uint;
typedef unsigned short ushort;
typedef __attribute__((ext_vector_type(8))) short bf16x8;
typedef __attribute__((ext_vector_type(4))) float f32x4;

// ---- bf16 helpers (storage-only bf16; math fp32 / MFMA fp32-acc) ----
__device__ __forceinline__ float bf2f(ushort u) { return __uint_as_float(((uint)u) << 16); }
__device__ __forceinline__ float bflo(uint u)   { return __uint_as_float(u << 16); }
__device__ __forceinline__ float bfhi(uint u)   { return __uint_as_float(u & 0xffff0000u); }
__device__ __forceinline__ ushort f2bf(float f) {
    uint u = __float_as_uint(f);
    u = (u + 0x7fffu + ((u >> 16) & 1u)) >> 16;   // RNE
    return (ushort)u;
}

// agent-scope (device) coherent load/store
__device__ __forceinline__ float ld_dev(const float* p) {
    return __hip_atomic_load(p, __ATOMIC_RELAXED, __HIP_MEMORY_SCOPE_AGENT);
}
__device__ __forceinline__ void st_dev(float* p, float v) {
    __hip_atomic_store(p, v, __ATOMIC_RELAXED, __HIP_MEMORY_SCOPE_AGENT);
}

// ---- prep (weight convert/transpose) FUSED with range histogram ----
__global__ __launch_bounds__(256) void prep_hist_kernel(
        const float* __restrict__ W0, const float* __restrict__ W1,
        const float* __restrict__ W2, ushort* __restrict__ Wt0,
        ushort* __restrict__ Wt1, ushort* __restrict__ Wt2,
        const int* __restrict__ dst, int* __restrict__ rhist,
        int* __restrict__ rowptr) {
    int t = blockIdx.x * 256 + threadIdx.x;
    if (t == 0) rowptr[NNODES] = NEDGES;
    if (t < 16384) {                       // W0 [128][128]
        int k = t >> 7, m = t & 127;
        Wt0[m * 128 + k] = f2bf(W0[t]);
    } else if (t < 32768) {                // W1 [128][128]
        int i = t - 16384;
        int k = i >> 7, m = i & 127;
        Wt1[m * 128 + k] = f2bf(W1[i]);
    } else if (t < 36864) {                // W2 [128][32]
        int i = t - 32768;
        int k = i >> 5, m = i & 31;
        Wt2[m * 128 + k] = f2bf(W2[i]);
    }
    __shared__ int cnt[NRANGE];
    for (int i = threadIdx.x; i < NRANGE; i += 256) cnt[i] = 0;
    __syncthreads();
    int base = blockIdx.x * RH_EPB;
    int end = base + RH_EPB; if (end > NEDGES) end = NEDGES;
    for (int i = base + threadIdx.x; i < end; i += 256) atomicAdd(&cnt[dst[i] >> 8], 1);
    __syncthreads();
    for (int i = threadIdx.x; i < NRANGE; i += 256)
        if (cnt[i]) atomicAdd(&rhist[i], cnt[i]);
}

// ==================== bucketed CSR build (scan fused redundantly per block) ====================
__global__ __launch_bounds__(256) void reorder_kernel(
        const int* __restrict__ src, const int* __restrict__ dst,
        const int* __restrict__ rhist, int* __restrict__ rcursor,
        uint* __restrict__ bucket) {
    __shared__ int cnt[NRANGE];
    __shared__ int bofs[NRANGE];
    __shared__ int rb[256];            // inclusive scan of rhist
    const int t = threadIdx.x;
    rb[t] = (t < NRANGE) ? rhist[t] : 0;
    if (t < NRANGE) cnt[t] = 0;
    __syncthreads();
    for (int off = 1; off < 256; off <<= 1) {
        int u = (t >= off) ? rb[t - off] : 0;
        __syncthreads();
        rb[t] += u;
        __syncthreads();
    }
    int base = blockIdx.x * RH_EPB;
    int end = base + RH_EPB; if (end > NEDGES) end = NEDGES;
    for (int i = base + t; i < end; i += 256) atomicAdd(&cnt[dst[i] >> 8], 1);
    __syncthreads();
    for (int i = t; i < NRANGE; i += 256) {
        int c = cnt[i];
        int ex = (i == 0) ? 0 : rb[i - 1];           // exclusive range base
        bofs[i] = c ? (ex + atomicAdd(&rcursor[i], c)) : 0;
    }
    __syncthreads();
    for (int i = t; i < NRANGE; i += 256) cnt[i] = 0;
    __syncthreads();
    for (int i = base + t; i < end; i += 256) {
        int d = dst[i], r = d >> 8;
        int loc = atomicAdd(&cnt[r], 1);
        bucket[bofs[r] + loc] = (uint)src[i] | ((uint)(d & 255) << 16);
    }
}

// AMPLIFIED x IREPS (idempotent: rewrites identical rowptr/csr_src)
__global__ __launch_bounds__(256) void range_csr_kernel(const int* __restrict__ rhist,
                                                        const uint* __restrict__ bucket,
                                                        int* __restrict__ rowptr,
                                                        int* __restrict__ csr_src) {
    __shared__ uint ebuf[MAXRE];
    __shared__ int deg[256], excl[256], cur[256];
    __shared__ int rb[256];
    const int r = blockIdx.x;
    const int t = threadIdx.x;
    rb[t] = (t < NRANGE) ? rhist[t] : 0;
    __syncthreads();
    for (int off = 1; off < 256; off <<= 1) {
        int u = (t >= off) ? rb[t - off] : 0;
        __syncthreads();
        rb[t] += u;
        __syncthreads();
    }
    const int b0 = (r == 0) ? 0 : rb[r - 1];
    const int cnt = rb[r] - b0;
    for (int rep = 0; rep < IREPS; ++rep) {
        __syncthreads();              // previous rep's stragglers done before re-init
        deg[t] = 0; cur[t] = 0;
        __syncthreads();
        for (int i = t; i < cnt; i += 256) {
            uint e = bucket[b0 + i];
            ebuf[i] = e;
            atomicAdd(&deg[e >> 16], 1);
        }
        __syncthreads();
        excl[t] = deg[t];
        __syncthreads();
        for (int off = 1; off < 256; off <<= 1) {
            int u = (t >= off) ? excl[t - off] : 0;
            __syncthreads();
            excl[t] += u;
            __syncthreads();
        }
        int myExcl = (t == 0) ? 0 : excl[t - 1];
        __syncthreads();
        excl[t] = myExcl;
        __syncthreads();
        int node = r * 256 + t;
        if (node < NNODES) rowptr[node] = b0 + myExcl;
        for (int i = t; i < cnt; i += 256) {
            uint e = ebuf[i];
            int dl = e >> 16;
            int loc = atomicAdd(&cur[dl], 1);
            csr_src[b0 + excl[dl] + loc] = (int)(e & 0xffffu);
        }
    }
}

// ==================== MFMA bf16 GEMM (AMPLIFIED x IREPS; idempotent) ====================
template <int M, bool HASBN>
__global__ __launch_bounds__(256) void gemm_mfma_kernel(
        const void* __restrict__ Xv, const ushort* __restrict__ Wt,
        const float* __restrict__ scale, const float* __restrict__ shift,
        const float* __restrict__ al, const float* __restrict__ ar,
        ushort* __restrict__ Y, float* __restrict__ el, float* __restrict__ er, int N) {
    constexpr int H   = M / 32;
    constexpr int BR  = (M == 128) ? 64 : 128;
    constexpr int RT  = (M == 128) ? 4 : 2;
    constexpr int CT  = 2;
    constexpr int LDK = 136;
    __shared__ ushort xs[BR][LDK];
    __shared__ float scs[128], shs[128];

    const int tid = threadIdx.x, wv = tid >> 6, lane = tid & 63;
    const int rowBase = blockIdx.x * BR;

    if (HASBN) {
        if (tid < 128) {
            scs[tid] = scale[tid];
            shs[tid] = shift[tid];
        }
        __syncthreads();
    }

    for (int rep = 0; rep < IREPS; ++rep) {
        __syncthreads();              // previous rep's Y-store reads of xs complete

        if (HASBN) {
            const ushort* X = (const ushort*)Xv;
            for (int i = tid; i < BR * 16; i += 256) {
                int rr = i >> 4, q = i & 15;
                int gr = rowBase + rr;
                uint4 u = make_uint4(0, 0, 0, 0);
                if (gr < N) u = *(const uint4*)(X + (size_t)gr * 128 + q * 8);
                uint arr[4] = {u.x, u.y, u.z, u.w};
                ushort* o = &xs[rr][q * 8];
#pragma unroll
                for (int j = 0; j < 4; ++j) {
                    int c = q * 8 + j * 2;
                    float lo = fmaxf(bflo(arr[j]) * scs[c] + shs[c], 0.f);
                    float hi = fmaxf(bfhi(arr[j]) * scs[c + 1] + shs[c + 1], 0.f);
                    o[j * 2]     = f2bf(lo);
                    o[j * 2 + 1] = f2bf(hi);
                }
            }
        } else {
            const float* X = (const float*)Xv;
            for (int i = tid; i < BR * 32; i += 256) {
                int rr = i >> 5, c4 = i & 31;
                int gr = rowBase + rr;
                float4 v = make_float4(0.f, 0.f, 0.f, 0.f);
                if (gr < N) v = *(const float4*)(X + (size_t)gr * 128 + c4 * 4);
                ushort* o = &xs[rr][c4 * 4];
                o[0] = f2bf(v.x); o[1] = f2bf(v.y); o[2] = f2bf(v.z); o[3] = f2bf(v.w);
            }
        }
        __syncthreads();

        const int waveRow = (M == 128) ? 0 : (wv * 32);
        const int waveCol = (M == 128) ? (wv * 32) : 0;
        const int fr = lane & 15, quad = lane >> 4;

        f32x4 acc[RT][CT];
#pragma unroll
        for (int rt = 0; rt < RT; ++rt)
#pragma unroll
            for (int ct = 0; ct < CT; ++ct) acc[rt][ct] = (f32x4){0.f, 0.f, 0.f, 0.f};

#pragma unroll
        for (int ks = 0; ks < 4; ++ks) {
            const int kb = ks * 32 + quad * 8;
            bf16x8 a[RT], b[CT];
#pragma unroll
            for (int rt = 0; rt < RT; ++rt) a[rt] = *(const bf16x8*)&xs[waveRow + rt * 16 + fr][kb];
#pragma unroll
            for (int ct = 0; ct < CT; ++ct)
                b[ct] = *(const bf16x8*)(Wt + (size_t)(waveCol + ct * 16 + fr) * 128 + kb);
#pragma unroll
            for (int rt = 0; rt < RT; ++rt)
#pragma unroll
                for (int ct = 0; ct < CT; ++ct)
                    acc[rt][ct] = __builtin_amdgcn_mfma_f32_16x16x32_bf16(a[rt], b[ct], acc[rt][ct], 0, 0, 0);
        }

        // fused el/er epilogue
        const float a0 = al[waveCol + fr],      a1 = al[waveCol + 16 + fr];
        const float g0 = ar[waveCol + fr],      g1 = ar[waveCol + 16 + fr];
        const int h = (M == 128) ? wv : 0;
#pragma unroll
        for (int rt = 0; rt < RT; ++rt)
#pragma unroll
            for (int rg = 0; rg < 4; ++rg) {
                float pe = acc[rt][0][rg] * a0 + acc[rt][1][rg] * a1;
                float pr = acc[rt][0][rg] * g0 + acc[rt][1][rg] * g1;
#pragma unroll
                for (int off = 1; off < 16; off <<= 1) {
                    pe += __shfl_xor(pe, off);
                    pr += __shfl_xor(pr, off);
                }
                int grow = rowBase + waveRow + rt * 16 + quad * 4 + rg;
                if (fr == 0 && grow < N) {
                    el[grow * H + h] = pe;
                    er[grow * H + h] = pr;
                }
            }

        // ---- coalesced Y store via LDS transpose (reuse xs) ----
        __syncthreads();   // all fragment reads of xs complete
#pragma unroll
        for (int rt = 0; rt < RT; ++rt)
#pragma unroll
            for (int ct = 0; ct < CT; ++ct)
#pragma unroll
                for (int rg = 0; rg < 4; ++rg) {
                    int lr = waveRow + rt * 16 + quad * 4 + rg;
                    int lc = waveCol + ct * 16 + fr;
                    xs[lr][lc] = f2bf(acc[rt][ct][rg]);
                }
        __syncthreads();
        if (M == 128) {
            int row = tid >> 2, seg = tid & 3;
            int gr = rowBase + row;
            if (gr < N) {
#pragma unroll
                for (int q = 0; q < 4; ++q) {
                    int col = (seg * 4 + q) * 8;
                    *(uint4*)(Y + (size_t)gr * 128 + col) = *(const uint4*)&xs[row][col];
                }
            }
        } else {
            int row = tid >> 1, hf = tid & 1;
            int gr = rowBase + row;
            if (gr < N) {
#pragma unroll
                for (int q = 0; q < 2; ++q) {
                    int col = (hf * 2 + q) * 8;
                    *(uint4*)(Y + (size_t)gr * 32 + col) = *(const uint4*)&xs[row][col];
                }
            }
        }
    }
}

// ==================== gather H=4 (AMPLIFIED x IREPS; idempotent) ====================
__global__ __launch_bounds__(256) void gat_gather4_kernel(
        const int* __restrict__ rowptr, const int* __restrict__ csr_src,
        const float* __restrict__ el, const float* __restrict__ er,
        const ushort* __restrict__ feat, const float* __restrict__ bias,
        ushort* __restrict__ xnext) {
    const int d = __builtin_amdgcn_readfirstlane(
        (int)((blockIdx.x * blockDim.x + threadIdx.x) >> 6));
    const int lane = threadIdx.x & 63;
    if (d >= NNODES) return;
    const int h   = lane >> 4;
    const int k   = lane & 15;
    const int grp = lane & 48;
    const int c0  = lane * 2;
    const int r0 = rowptr[d];
    const int deg = rowptr[d + 1] - r0;
    const float erh = er[d * 4 + h];

    for (int rep = 0; rep < IREPS; ++rep) {
        float dnm = 0.f, ax = 0.f, ay = 0.f;
        int s_c = 0; float ex_c = 0.f;
        if (k < deg) {
            s_c = csr_src[r0 + k];
            float v = el[s_c * 4 + h] + erh;
            v = v > 0.f ? v : NEG_SLOPE * v;
            ex_c = __expf(v);
        }
        for (int j0 = 0; j0 < deg; j0 += 16) {
            const int nidx = j0 + 16 + k;
            int s_n = 0;
            if (nidx < deg) s_n = csr_src[r0 + nidx];
            dnm += ex_c;
            uint u[16];
#pragma unroll
            for (int jj = 0; jj < 16; ++jj) {
                int sj = __builtin_amdgcn_readlane(s_c, jj);
                u[jj] = *(const uint*)(feat + (size_t)sj * 128 + c0);
            }
            float ex_n = 0.f;
            if (nidx < deg) {
                float v = el[s_n * 4 + h] + erh;
                v = v > 0.f ? v : NEG_SLOPE * v;
                ex_n = __expf(v);
            }
#pragma unroll
            for (int jj = 0; jj < 16; ++jj) {
                float exj = __shfl(ex_c, grp + jj);
                ax = fmaf(exj, bflo(u[jj]), ax);
                ay = fmaf(exj, bfhi(u[jj]), ay);
            }
            s_c = s_n; ex_c = ex_n;
        }
#pragma unroll
        for (int off = 1; off < 16; off <<= 1) dnm += __shfl_xor(dnm, off);
        float inv = (dnm > 0.f) ? 1.f / dnm : 0.f;
        float vx = ax * inv + bias[c0];
        float vy = ay * inv + bias[c0 + 1];
        uint pk = ((uint)f2bf(vy) << 16) | (uint)f2bf(vx);
        *(uint*)(xnext + (size_t)d * 128 + c0) = pk;
    }
}

// ---- BN stats + FUSED finalize (last-block-done; NOT amplified: counter) ----
__global__ __launch_bounds__(256) void bn_stats_kernel(
        const ushort* __restrict__ X, float* __restrict__ psum, float* __restrict__ psumsq,
        const float* __restrict__ g, const float* __restrict__ beta,
        float* __restrict__ scale, float* __restrict__ shift, int* __restrict__ counter) {
    const uint* X32 = (const uint*)X;          // [N][64] packed col pairs
    int uc = threadIdx.x & 63;                 // uint col (cols 2uc, 2uc+1)
    int rq = threadIdx.x >> 6;                 // row quarter
    int r0 = blockIdx.x * BN_RPB;
    float s0 = 0.f, s1 = 0.f, ss0 = 0.f, ss1 = 0.f;
    for (int r = r0 + rq; r < r0 + BN_RPB; r += 4) {
        uint u = X32[(size_t)r * 64 + uc];
        float lo = bflo(u), hi = bfhi(u);
        s0 += lo; ss0 += lo * lo;
        s1 += hi; ss1 += hi * hi;
    }
    __shared__ float red[4][256], redsq[4][256];
    red[rq][uc * 2] = s0;      red[rq][uc * 2 + 1] = s1;
    redsq[rq][uc * 2] = ss0;   redsq[rq][uc * 2 + 1] = ss1;
    __syncthreads();
    int t = threadIdx.x;
    if (t < 128) {
        st_dev(&psum[blockIdx.x * 128 + t], red[0][t] + red[1][t] + red[2][t] + red[3][t]);
    } else {
        int c = t - 128;
        st_dev(&psumsq[blockIdx.x * 128 + c], redsq[0][c] + redsq[1][c] + redsq[2][c] + redsq[3][c]);
    }
    __syncthreads();   // drains vmcnt(0): all st_dev complete before counter bump
    __shared__ int isLast;
    if (t == 0) isLast = (atomicAdd(counter, 1) == (int)gridDim.x - 1);
    __syncthreads();
    if (!isLast) return;
    __threadfence();   // single acquire fence, last block only
    if (t < 128) {
        float s = 0.f, ss = 0.f;
        for (int b = 0; b < BN_NB; ++b) {
            s += ld_dev(&psum[b * 128 + t]);
            ss += ld_dev(&psumsq[b * 128 + t]);
        }
        const float inv = 1.f / NNODES;
        float mu = s * inv;
        float var = ss * inv - mu * mu;
        float sc = g[t] * rsqrtf(var + BN_EPS);
        scale[t] = sc;
        shift[t] = beta[t] - mu * sc;
    }
}

// ==================== gather H=1 with fused graph pooling (NOT amplified: atomics) ====================
__global__ __launch_bounds__(256) void gat_gather1_kernel(
        const int* __restrict__ rowptr, const int* __restrict__ csr_src,
        const float* __restrict__ el, const float* __restrict__ er,
        const ushort* __restrict__ feat, const float* __restrict__ bias,
        const int* __restrict__ gid, float* __restrict__ pooled) {
    const int d = __builtin_amdgcn_readfirstlane(
        (int)((blockIdx.x * blockDim.x + threadIdx.x) >> 6));
    int lane = threadIdx.x & 63;
    if (d >= NNODES) return;
    const int r0 = rowptr[d];
    const int deg = rowptr[d + 1] - r0;
    const int half = lane >> 5;
    const int c    = lane & 31;
    const float erh = er[d];
    float dnm = 0.f, acc = 0.f;

    for (int j0 = 0; j0 < deg; j0 += 32) {
        int eidx = j0 + (lane & 31);
        int s_e = 0;
        float ex = 0.f;
        if (eidx < deg) {
            s_e = csr_src[r0 + eidx];
            float v = el[s_e] + erh;
            v = v > 0.f ? v : NEG_SLOPE * v;
            ex = __expf(v);
        }
        dnm += ex;
        ushort u[16];
#pragma unroll
        for (int jj = 0; jj < 16; ++jj) {
            int sj = __shfl(s_e, 2 * jj + half);
            u[jj] = feat[(size_t)sj * 32 + c];
        }
#pragma unroll
        for (int jj = 0; jj < 16; ++jj) {
            float exj = __shfl(ex, 2 * jj + half);
            acc = fmaf(exj, bf2f(u[jj]), acc);
        }
    }
#pragma unroll
    for (int off = 1; off < 32; off <<= 1) dnm += __shfl_xor(dnm, off);
    acc += __shfl_down(acc, 32);
    if (half == 0) {
        float inv = (dnm > 0.f) ? 1.f / dnm : 0.f;
        atomicAdd(&pooled[gid[d] * 32 + c], acc * inv + bias[c]);
    }
}

// ---- classifier ----
__global__ void classify_kernel(const float* __restrict__ pooled, const float* __restrict__ Wc,
                                const float* __restrict__ bc, float* __restrict__ out) {
    int t = blockIdx.x * blockDim.x + threadIdx.x;
    if (t >= NGRAPHS * 10) return;
    int gIdx = t / 10, j = t % 10;
    float s = bc[j];
#pragma unroll
    for (int c = 0; c < 32; ++c) s += pooled[gIdx * 32 + c] * Wc[c * 10 + j];
    out[t] = s;
}

extern "C" void kernel_launch(void* const* d_in, const int* in_sizes, int n_in,
                              void* d_out, int out_size, void* d_ws, size_t ws_size,
                              hipStream_t stream) {
    const float* x     = (const float*)d_in[0];
    const int*   esrc  = (const int*)d_in[1];
    const int*   edst  = (const int*)d_in[2];
    const int*   gid   = (const int*)d_in[3];
    const float* W0    = (const float*)d_in[4];
    const float* al0   = (const float*)d_in[5];
    const float* ar0   = (const float*)d_in[6];
    const float* b0    = (const float*)d_in[7];
    const float* W1    = (const float*)d_in[8];
    const float* al1   = (const float*)d_in[9];
    const float* ar1   = (const float*)d_in[10];
    const float* b1    = (const float*)d_in[11];
    const float* W2    = (const float*)d_in[12];
    const float* al2   = (const float*)d_in[13];
    const float* ar2   = (const float*)d_in[14];
    const float* b2    = (const float*)d_in[15];
    const float* g0    = (const float*)d_in[16];
    const float* beta0 = (const float*)d_in[17];
    const float* g1    = (const float*)d_in[18];
    const float* beta1 = (const float*)d_in[19];
    const float* Wc    = (const float*)d_in[20];
    const float* bc    = (const float*)d_in[21];

    // ---- workspace layout: one contiguous zero-init region first ----
    int*   counters = (int*)d_ws;                             // [8]: 0=bn0 1=bn1
    int*   rhist    = counters + 8;                           // [196]
    int*   rcursor  = rhist + NRANGE;                         // [196]
    float* pooled   = (float*)(rcursor + NRANGE);             // [500*32]
    float* psum     = pooled + NGRAPHS * 32;                  // [400*128]
    float* psumsq   = psum + BN_NB * 128;                     // [400*128]
    float* scale0   = psumsq + BN_NB * 128;                   // [128]
    float* shift0   = scale0 + 128;
    float* scale1   = shift0 + 128;
    float* shift1   = scale1 + 128;
    int*   rowptr   = (int*)(shift1 + 128);                   // [N+1]
    int*   csr_src  = rowptr + NNODES + 1;                    // [E]
    uint*  bucket   = (uint*)(csr_src + NEDGES);              // [E]
    size_t ofs = (size_t)((int*)(bucket + NEDGES) - (int*)d_ws);
    ofs = (ofs + 3) & ~(size_t)3;                             // 16B alignment
    ushort* featbf = (ushort*)((int*)d_ws + ofs);             // [N,128] bf16 GEMM out
    ushort* xnext  = featbf + (size_t)NNODES * 128;           // [N,128] bf16 gather out / GEMM in
    float*  el     = (float*)(xnext + (size_t)NNODES * 128);  // [N,4]
    float*  er     = el + (size_t)NNODES * 4;                 // [N,4]
    ushort* Wt0    = (ushort*)(er + (size_t)NNODES * 4);      // [128,128]
    ushort* Wt1    = Wt0 + 128 * 128;                         // [128,128]
    ushort* Wt2    = Wt1 + 128 * 128;                         // [32,128]

    const int T = 256;
    float* out = (float*)d_out;

    // ---- single zero-init (counters + rhist + rcursor + pooled) ----
    hipMemsetAsync(counters, 0, (size_t)(8 + NRANGE + NRANGE + NGRAPHS * 32) * 4, stream);
    prep_hist_kernel<<<RH_NB, T, 0, stream>>>(W0, W1, W2, Wt0, Wt1, Wt2, edst, rhist, rowptr);

    // ---- bucketed CSR build (scan folded into reorder/range_csr) ----
    reorder_kernel<<<RH_NB, T, 0, stream>>>(esrc, edst, rhist, rcursor, bucket);
    range_csr_kernel<<<NRANGE, T, 0, stream>>>(rhist, bucket, rowptr, csr_src);

    const int GATHER_BLOCKS  = (NNODES * 64) / T;             // exact: 12500
    const int GEMM128_BLOCKS = (NNODES + 63) / 64;
    const int GEMM32_BLOCKS  = (NNODES + 127) / 128;

    // ================= Layer 0 =================
    gemm_mfma_kernel<128, false><<<GEMM128_BLOCKS, T, 0, stream>>>(
        x, Wt0, nullptr, nullptr, al0, ar0, featbf, el, er, NNODES);
    gat_gather4_kernel<<<GATHER_BLOCKS, T, 0, stream>>>(rowptr, csr_src, el, er, featbf, b0, xnext);
    bn_stats_kernel<<<BN_NB, T, 0, stream>>>(xnext, psum, psumsq, g0, beta0, scale0, shift0,
                                             &counters[0]);

    // ================= Layer 1 =================
    gemm_mfma_kernel<128, true><<<GEMM128_BLOCKS, T, 0, stream>>>(
        xnext, Wt1, scale0, shift0, al1, ar1, featbf, el, er, NNODES);
    gat_gather4_kernel<<<GATHER_BLOCKS, T, 0, stream>>>(rowptr, csr_src, el, er, featbf, b1, xnext);
    bn_stats_kernel<<<BN_NB, T, 0, stream>>>(xnext, psum, psumsq, g1, beta1, scale1, shift1,
                                             &counters[1]);

    // ================= Layer 2 (H=1, D=32) =================
    gemm_mfma_kernel<32, true><<<GEMM32_BLOCKS, T, 0, stream>>>(
        xnext, Wt2, scale1, shift1, al2, ar2, featbf, el, er, NNODES);
    gat_gather1_kernel<<<GATHER_BLOCKS, T, 0, stream>>>(rowptr, csr_src, el, er, featbf, b2,
                                                        gid, pooled);

    // ================= Classify =================
    classify_kernel<<<(NGRAPHS * 10 + T - 1) / T, T, 0, stream>>>(pooled, Wc, bc, out);
}

// Round 6
// 355.785 us; speedup vs baseline: 2.5272x; 2.5272x over previous
//
#include <hip/hip_runtime.h>
#include <math.h>

#define NNODES 50000
#define NEDGES 800000
#define NGRAPHS 500
#define NEG_SLOPE 0.2f
#define BN_EPS 1e-5f
#define NRANGE 196            // ceil(50000/256) node ranges of 256
#define RH_EPB 2048           // edges per block in range hist/reorder (391 blocks)
#define RH_NB ((NEDGES + RH_EPB - 1) / RH_EPB)
#define MAXRE 5120            // LDS stage capacity per range
#define BN_NB 400
#define BN_RPB 125

typedef unsigned int uint;
typedef unsigned short ushort;
typedef __attribute__((ext_vector_type(8))) short bf16x8;
typedef __attribute__((ext_vector_type(4))) float f32x4;

// ---- bf16 helpers (storage-only bf16; math fp32 / MFMA fp32-acc) ----
__device__ __forceinline__ float bf2f(ushort u) { return __uint_as_float(((uint)u) << 16); }
__device__ __forceinline__ float bflo(uint u)   { return __uint_as_float(u << 16); }
__device__ __forceinline__ float bfhi(uint u)   { return __uint_as_float(u & 0xffff0000u); }
__device__ __forceinline__ ushort f2bf(float f) {
    uint u = __float_as_uint(f);
    u = (u + 0x7fffu + ((u >> 16) & 1u)) >> 16;   // RNE
    return (ushort)u;
}

// agent-scope (device) coherent load/store
__device__ __forceinline__ float ld_dev(const float* p) {
    return __hip_atomic_load(p, __ATOMIC_RELAXED, __HIP_MEMORY_SCOPE_AGENT);
}
__device__ __forceinline__ void st_dev(float* p, float v) {
    __hip_atomic_store(p, v, __ATOMIC_RELAXED, __HIP_MEMORY_SCOPE_AGENT);
}

// ---- prep (weight convert/transpose) FUSED with range histogram ----
__global__ __launch_bounds__(256) void prep_hist_kernel(
        const float* __restrict__ W0, const float* __restrict__ W1,
        const float* __restrict__ W2, ushort* __restrict__ Wt0,
        ushort* __restrict__ Wt1, ushort* __restrict__ Wt2,
        const int* __restrict__ dst, int* __restrict__ rhist,
        int* __restrict__ rowptr) {
    int t = blockIdx.x * 256 + threadIdx.x;
    if (t == 0) rowptr[NNODES] = NEDGES;
    if (t < 16384) {                       // W0 [128][128]
        int k = t >> 7, m = t & 127;
        Wt0[m * 128 + k] = f2bf(W0[t]);
    } else if (t < 32768) {                // W1 [128][128]
        int i = t - 16384;
        int k = i >> 7, m = i & 127;
        Wt1[m * 128 + k] = f2bf(W1[i]);
    } else if (t < 36864) {                // W2 [128][32]
        int i = t - 32768;
        int k = i >> 5, m = i & 31;
        Wt2[m * 128 + k] = f2bf(W2[i]);
    }
    __shared__ int cnt[NRANGE];
    for (int i = threadIdx.x; i < NRANGE; i += 256) cnt[i] = 0;
    __syncthreads();
    int base = blockIdx.x * RH_EPB;
    int end = base + RH_EPB; if (end > NEDGES) end = NEDGES;
    for (int i = base + threadIdx.x; i < end; i += 256) atomicAdd(&cnt[dst[i] >> 8], 1);
    __syncthreads();
    for (int i = threadIdx.x; i < NRANGE; i += 256)
        if (cnt[i]) atomicAdd(&rhist[i], cnt[i]);
}

// ==================== reorder (scan fused redundantly per block) ====================
__global__ __launch_bounds__(256) void reorder_kernel(
        const int* __restrict__ src, const int* __restrict__ dst,
        const int* __restrict__ rhist, int* __restrict__ rcursor,
        uint* __restrict__ bucket) {
    __shared__ int cnt[NRANGE];
    __shared__ int bofs[NRANGE];
    __shared__ int rb[256];            // inclusive scan of rhist
    const int t = threadIdx.x;
    rb[t] = (t < NRANGE) ? rhist[t] : 0;
    if (t < NRANGE) cnt[t] = 0;
    __syncthreads();
    for (int off = 1; off < 256; off <<= 1) {
        int u = (t >= off) ? rb[t - off] : 0;
        __syncthreads();
        rb[t] += u;
        __syncthreads();
    }
    int base = blockIdx.x * RH_EPB;
    int end = base + RH_EPB; if (end > NEDGES) end = NEDGES;
    for (int i = base + t; i < end; i += 256) atomicAdd(&cnt[dst[i] >> 8], 1);
    __syncthreads();
    for (int i = t; i < NRANGE; i += 256) {
        int c = cnt[i];
        int ex = (i == 0) ? 0 : rb[i - 1];           // exclusive range base
        bofs[i] = c ? (ex + atomicAdd(&rcursor[i], c)) : 0;
    }
    __syncthreads();
    for (int i = t; i < NRANGE; i += 256) cnt[i] = 0;
    __syncthreads();
    for (int i = base + t; i < end; i += 256) {
        int d = dst[i], r = d >> 8;
        int loc = atomicAdd(&cnt[r], 1);
        bucket[bofs[r] + loc] = (uint)src[i] | ((uint)(d & 255) << 16);
    }
}

// ==================== FUSED: range CSR build (blocks 0..195) + GEMM layer0 (rest) ====
// The two roles are independent in the DAG (CSR feeds gathers; GEMM0 feeds el/er/feat).
// Fusing them into one launch lets low-occupancy CSR work overlap the GEMM instead of
// serializing on the in-order stream. Branch is block-uniform.
__global__ __launch_bounds__(256) void csr_gemm0_kernel(
        const int* __restrict__ rhist, const uint* __restrict__ bucket,
        int* __restrict__ rowptr, int* __restrict__ csr_src,
        const float* __restrict__ X, const ushort* __restrict__ Wt,
        const float* __restrict__ al, const float* __restrict__ ar,
        ushort* __restrict__ Y, float* __restrict__ el, float* __restrict__ er) {
    __shared__ union {
        struct { uint ebuf[MAXRE]; int deg[256]; int excl[256]; int cur[256]; int rb[256]; } c;
        struct { ushort xs[64][136]; } g;
    } sh;
    const int t = threadIdx.x;

    if (blockIdx.x < NRANGE) {
        // ---------------- CSR role ----------------
        const int r = blockIdx.x;
        sh.c.rb[t] = (t < NRANGE) ? rhist[t] : 0;
        __syncthreads();
        for (int off = 1; off < 256; off <<= 1) {
            int u = (t >= off) ? sh.c.rb[t - off] : 0;
            __syncthreads();
            sh.c.rb[t] += u;
            __syncthreads();
        }
        const int b0 = (r == 0) ? 0 : sh.c.rb[r - 1];
        const int cnt = sh.c.rb[r] - b0;
        sh.c.deg[t] = 0; sh.c.cur[t] = 0;
        __syncthreads();
        for (int i = t; i < cnt; i += 256) {
            uint e = bucket[b0 + i];
            sh.c.ebuf[i] = e;
            atomicAdd(&sh.c.deg[e >> 16], 1);
        }
        __syncthreads();
        sh.c.excl[t] = sh.c.deg[t];
        __syncthreads();
        for (int off = 1; off < 256; off <<= 1) {
            int u = (t >= off) ? sh.c.excl[t - off] : 0;
            __syncthreads();
            sh.c.excl[t] += u;
            __syncthreads();
        }
        int myExcl = (t == 0) ? 0 : sh.c.excl[t - 1];
        __syncthreads();
        sh.c.excl[t] = myExcl;
        __syncthreads();
        int node = r * 256 + t;
        if (node < NNODES) rowptr[node] = b0 + myExcl;
        for (int i = t; i < cnt; i += 256) {
            uint e = sh.c.ebuf[i];
            int dl = e >> 16;
            int loc = atomicAdd(&sh.c.cur[dl], 1);
            csr_src[b0 + sh.c.excl[dl] + loc] = (int)(e & 0xffffu);
        }
        return;
    }

    // ---------------- GEMM role (M=128, fp32 input, no BN) ----------------
    const int wv = t >> 6, lane = t & 63;
    const int rowBase = (int)(blockIdx.x - NRANGE) * 64;
    const int N = NNODES;

    for (int i = t; i < 64 * 32; i += 256) {
        int rr = i >> 5, c4 = i & 31;
        int gr = rowBase + rr;
        float4 v = make_float4(0.f, 0.f, 0.f, 0.f);
        if (gr < N) v = *(const float4*)(X + (size_t)gr * 128 + c4 * 4);
        ushort* o = &sh.g.xs[rr][c4 * 4];
        o[0] = f2bf(v.x); o[1] = f2bf(v.y); o[2] = f2bf(v.z); o[3] = f2bf(v.w);
    }
    __syncthreads();

    const int waveCol = wv * 32;
    const int fr = lane & 15, quad = lane >> 4;

    f32x4 acc[4][2];
#pragma unroll
    for (int rt = 0; rt < 4; ++rt)
#pragma unroll
        for (int ct = 0; ct < 2; ++ct) acc[rt][ct] = (f32x4){0.f, 0.f, 0.f, 0.f};

#pragma unroll
    for (int ks = 0; ks < 4; ++ks) {
        const int kb = ks * 32 + quad * 8;
        bf16x8 a[4], b[2];
#pragma unroll
        for (int rt = 0; rt < 4; ++rt) a[rt] = *(const bf16x8*)&sh.g.xs[rt * 16 + fr][kb];
#pragma unroll
        for (int ct = 0; ct < 2; ++ct)
            b[ct] = *(const bf16x8*)(Wt + (size_t)(waveCol + ct * 16 + fr) * 128 + kb);
#pragma unroll
        for (int rt = 0; rt < 4; ++rt)
#pragma unroll
            for (int ct = 0; ct < 2; ++ct)
                acc[rt][ct] = __builtin_amdgcn_mfma_f32_16x16x32_bf16(a[rt], b[ct], acc[rt][ct], 0, 0, 0);
    }

    // fused el/er epilogue
    const float a0 = al[waveCol + fr],      a1 = al[waveCol + 16 + fr];
    const float g0 = ar[waveCol + fr],      g1 = ar[waveCol + 16 + fr];
    const int h = wv;
#pragma unroll
    for (int rt = 0; rt < 4; ++rt)
#pragma unroll
        for (int rg = 0; rg < 4; ++rg) {
            float pe = acc[rt][0][rg] * a0 + acc[rt][1][rg] * a1;
            float pr = acc[rt][0][rg] * g0 + acc[rt][1][rg] * g1;
#pragma unroll
            for (int off = 1; off < 16; off <<= 1) {
                pe += __shfl_xor(pe, off);
                pr += __shfl_xor(pr, off);
            }
            int grow = rowBase + rt * 16 + quad * 4 + rg;
            if (fr == 0 && grow < N) {
                el[grow * 4 + h] = pe;
                er[grow * 4 + h] = pr;
            }
        }

    // coalesced Y store via LDS transpose (reuse xs)
    __syncthreads();
#pragma unroll
    for (int rt = 0; rt < 4; ++rt)
#pragma unroll
        for (int ct = 0; ct < 2; ++ct)
#pragma unroll
            for (int rg = 0; rg < 4; ++rg) {
                int lr = rt * 16 + quad * 4 + rg;
                int lc = waveCol + ct * 16 + fr;
                sh.g.xs[lr][lc] = f2bf(acc[rt][ct][rg]);
            }
    __syncthreads();
    {
        int row = t >> 2, seg = t & 3;
        int gr = rowBase + row;
        if (gr < N) {
#pragma unroll
            for (int q = 0; q < 4; ++q) {
                int col = (seg * 4 + q) * 8;
                *(uint4*)(Y + (size_t)gr * 128 + col) = *(const uint4*)&sh.g.xs[row][col];
            }
        }
    }
}

// ==================== MFMA bf16 GEMM, fused BN/ReLU input + el/er epilogue ====================
template <int M, bool HASBN>
__global__ __launch_bounds__(256) void gemm_mfma_kernel(
        const void* __restrict__ Xv, const ushort* __restrict__ Wt,
        const float* __restrict__ scale, const float* __restrict__ shift,
        const float* __restrict__ al, const float* __restrict__ ar,
        ushort* __restrict__ Y, float* __restrict__ el, float* __restrict__ er, int N) {
    constexpr int H   = M / 32;
    constexpr int BR  = (M == 128) ? 64 : 128;
    constexpr int RT  = (M == 128) ? 4 : 2;
    constexpr int CT  = 2;
    constexpr int LDK = 136;
    __shared__ ushort xs[BR][LDK];
    __shared__ float scs[128], shs[128];

    const int tid = threadIdx.x, wv = tid >> 6, lane = tid & 63;
    const int rowBase = blockIdx.x * BR;

    if (HASBN) {
        if (tid < 128) {
            scs[tid] = scale[tid];
            shs[tid] = shift[tid];
        }
        __syncthreads();
    }

    if (HASBN) {
        const ushort* X = (const ushort*)Xv;
        for (int i = tid; i < BR * 16; i += 256) {
            int rr = i >> 4, q = i & 15;
            int gr = rowBase + rr;
            uint4 u = make_uint4(0, 0, 0, 0);
            if (gr < N) u = *(const uint4*)(X + (size_t)gr * 128 + q * 8);
            uint arr[4] = {u.x, u.y, u.z, u.w};
            ushort* o = &xs[rr][q * 8];
#pragma unroll
            for (int j = 0; j < 4; ++j) {
                int c = q * 8 + j * 2;
                float lo = fmaxf(bflo(arr[j]) * scs[c] + shs[c], 0.f);
                float hi = fmaxf(bfhi(arr[j]) * scs[c + 1] + shs[c + 1], 0.f);
                o[j * 2]     = f2bf(lo);
                o[j * 2 + 1] = f2bf(hi);
            }
        }
    } else {
        const float* X = (const float*)Xv;
        for (int i = tid; i < BR * 32; i += 256) {
            int rr = i >> 5, c4 = i & 31;
            int gr = rowBase + rr;
            float4 v = make_float4(0.f, 0.f, 0.f, 0.f);
            if (gr < N) v = *(const float4*)(X + (size_t)gr * 128 + c4 * 4);
            ushort* o = &xs[rr][c4 * 4];
            o[0] = f2bf(v.x); o[1] = f2bf(v.y); o[2] = f2bf(v.z); o[3] = f2bf(v.w);
        }
    }
    __syncthreads();

    const int waveRow = (M == 128) ? 0 : (wv * 32);
    const int waveCol = (M == 128) ? (wv * 32) : 0;
    const int fr = lane & 15, quad = lane >> 4;

    f32x4 acc[RT][CT];
#pragma unroll
    for (int rt = 0; rt < RT; ++rt)
#pragma unroll
        for (int ct = 0; ct < CT; ++ct) acc[rt][ct] = (f32x4){0.f, 0.f, 0.f, 0.f};

#pragma unroll
    for (int ks = 0; ks < 4; ++ks) {
        const int kb = ks * 32 + quad * 8;
        bf16x8 a[RT], b[CT];
#pragma unroll
        for (int rt = 0; rt < RT; ++rt) a[rt] = *(const bf16x8*)&xs[waveRow + rt * 16 + fr][kb];
#pragma unroll
        for (int ct = 0; ct < CT; ++ct)
            b[ct] = *(const bf16x8*)(Wt + (size_t)(waveCol + ct * 16 + fr) * 128 + kb);
#pragma unroll
        for (int rt = 0; rt < RT; ++rt)
#pragma unroll
            for (int ct = 0; ct < CT; ++ct)
                acc[rt][ct] = __builtin_amdgcn_mfma_f32_16x16x32_bf16(a[rt], b[ct], acc[rt][ct], 0, 0, 0);
    }

    // fused el/er epilogue
    const float a0 = al[waveCol + fr],      a1 = al[waveCol + 16 + fr];
    const float g0 = ar[waveCol + fr],      g1 = ar[waveCol + 16 + fr];
    const int h = (M == 128) ? wv : 0;
#pragma unroll
    for (int rt = 0; rt < RT; ++rt)
#pragma unroll
        for (int rg = 0; rg < 4; ++rg) {
            float pe = acc[rt][0][rg] * a0 + acc[rt][1][rg] * a1;
            float pr = acc[rt][0][rg] * g0 + acc[rt][1][rg] * g1;
#pragma unroll
            for (int off = 1; off < 16; off <<= 1) {
                pe += __shfl_xor(pe, off);
                pr += __shfl_xor(pr, off);
            }
            int grow = rowBase + waveRow + rt * 16 + quad * 4 + rg;
            if (fr == 0 && grow < N) {
                el[grow * H + h] = pe;
                er[grow * H + h] = pr;
            }
        }

    // ---- coalesced Y store via LDS transpose (reuse xs) ----
    __syncthreads();
#pragma unroll
    for (int rt = 0; rt < RT; ++rt)
#pragma unroll
        for (int ct = 0; ct < CT; ++ct)
#pragma unroll
            for (int rg = 0; rg < 4; ++rg) {
                int lr = waveRow + rt * 16 + quad * 4 + rg;
                int lc = waveCol + ct * 16 + fr;
                xs[lr][lc] = f2bf(acc[rt][ct][rg]);
            }
    __syncthreads();
    if (M == 128) {
        int row = tid >> 2, seg = tid & 3;
        int gr = rowBase + row;
        if (gr < N) {
#pragma unroll
            for (int q = 0; q < 4; ++q) {
                int col = (seg * 4 + q) * 8;
                *(uint4*)(Y + (size_t)gr * 128 + col) = *(const uint4*)&xs[row][col];
            }
        }
    } else {
        int row = tid >> 1, hf = tid & 1;
        int gr = rowBase + row;
        if (gr < N) {
#pragma unroll
            for (int q = 0; q < 2; ++q) {
                int col = (hf * 2 + q) * 8;
                *(uint4*)(Y + (size_t)gr * 32 + col) = *(const uint4*)&xs[row][col];
            }
        }
    }
}

// ==================== gather H=4: ping-pong double-buffered chunks ====================
// While MACs consume chunk A's feat regs, chunk B's csr->el->exp->feat loads are in
// flight (and vice versa). deg is wave-uniform so all guards are uniform branches.
__global__ __launch_bounds__(256) void gat_gather4_kernel(
        const int* __restrict__ rowptr, const int* __restrict__ csr_src,
        const float* __restrict__ el, const float* __restrict__ er,
        const ushort* __restrict__ feat, const float* __restrict__ bias,
        ushort* __restrict__ xnext) {
    const int d = __builtin_amdgcn_readfirstlane(
        (int)((blockIdx.x * blockDim.x + threadIdx.x) >> 6));
    const int lane = threadIdx.x & 63;
    if (d >= NNODES) return;
    const int h   = lane >> 4;
    const int k   = lane & 15;
    const int grp = lane & 48;
    const int c0  = lane * 2;
    const int r0 = rowptr[d];
    const int deg = rowptr[d + 1] - r0;
    const float erh = er[d * 4 + h];
    float dnm = 0.f, ax = 0.f, ay = 0.f;

    // prologue: chunk A = edges [0,16)
    int sA = 0; float exA = 0.f;
    if (k < deg) {
        sA = csr_src[r0 + k];
        float v = el[sA * 4 + h] + erh;
        v = v > 0.f ? v : NEG_SLOPE * v;
        exA = __expf(v);
    }
    uint uA[16], uB[16];
#pragma unroll
    for (int jj = 0; jj < 16; ++jj) {
        int sj = __builtin_amdgcn_readlane(sA, jj);
        uA[jj] = *(const uint*)(feat + (size_t)sj * 128 + c0);
    }

    for (int j0 = 0;;) {
        // stage chunk B = [j0+16, j0+32) while uA is in flight
        const bool hasB = (j0 + 16) < deg;
        int sB = 0; float exB = 0.f;
        if (hasB) {
            int eidx = j0 + 16 + k;
            if (eidx < deg) {
                sB = csr_src[r0 + eidx];
                float v = el[sB * 4 + h] + erh;
                v = v > 0.f ? v : NEG_SLOPE * v;
                exB = __expf(v);
            }
#pragma unroll
            for (int jj = 0; jj < 16; ++jj) {
                int sj = __builtin_amdgcn_readlane(sB, jj);
                uB[jj] = *(const uint*)(feat + (size_t)sj * 128 + c0);
            }
        }
        // consume chunk A
        dnm += exA;
#pragma unroll
        for (int jj = 0; jj < 16; ++jj) {
            float e = __shfl(exA, grp + jj);
            ax = fmaf(e, bflo(uA[jj]), ax);
            ay = fmaf(e, bfhi(uA[jj]), ay);
        }
        if (!hasB) break;
        j0 += 16;

        // stage next chunk A = [j0+16, j0+32) while uB is in flight
        const bool hasA2 = (j0 + 16) < deg;
        sA = 0; exA = 0.f;
        if (hasA2) {
            int eidx = j0 + 16 + k;
            if (eidx < deg) {
                sA = csr_src[r0 + eidx];
                float v = el[sA * 4 + h] + erh;
                v = v > 0.f ? v : NEG_SLOPE * v;
                exA = __expf(v);
            }
#pragma unroll
            for (int jj = 0; jj < 16; ++jj) {
                int sj = __builtin_amdgcn_readlane(sA, jj);
                uA[jj] = *(const uint*)(feat + (size_t)sj * 128 + c0);
            }
        }
        // consume chunk B
        dnm += exB;
#pragma unroll
        for (int jj = 0; jj < 16; ++jj) {
            float e = __shfl(exB, grp + jj);
            ax = fmaf(e, bflo(uB[jj]), ax);
            ay = fmaf(e, bfhi(uB[jj]), ay);
        }
        if (!hasA2) break;
        j0 += 16;
    }
#pragma unroll
    for (int off = 1; off < 16; off <<= 1) dnm += __shfl_xor(dnm, off);
    float inv = (dnm > 0.f) ? 1.f / dnm : 0.f;
    float vx = ax * inv + bias[c0];
    float vy = ay * inv + bias[c0 + 1];
    uint pk = ((uint)f2bf(vy) << 16) | (uint)f2bf(vx);
    *(uint*)(xnext + (size_t)d * 128 + c0) = pk;
}

// ---- BN stats + FUSED finalize (last-block-done; 400 blocks; no per-block fence) ----
__global__ __launch_bounds__(256) void bn_stats_kernel(
        const ushort* __restrict__ X, float* __restrict__ psum, float* __restrict__ psumsq,
        const float* __restrict__ g, const float* __restrict__ beta,
        float* __restrict__ scale, float* __restrict__ shift, int* __restrict__ counter) {
    const uint* X32 = (const uint*)X;          // [N][64] packed col pairs
    int uc = threadIdx.x & 63;                 // uint col (cols 2uc, 2uc+1)
    int rq = threadIdx.x >> 6;                 // row quarter
    int r0 = blockIdx.x * BN_RPB;
    float s0 = 0.f, s1 = 0.f, ss0 = 0.f, ss1 = 0.f;
    for (int r = r0 + rq; r < r0 + BN_RPB; r += 4) {
        uint u = X32[(size_t)r * 64 + uc];
        float lo = bflo(u), hi = bfhi(u);
        s0 += lo; ss0 += lo * lo;
        s1 += hi; ss1 += hi * hi;
    }
    __shared__ float red[4][256], redsq[4][256];
    red[rq][uc * 2] = s0;      red[rq][uc * 2 + 1] = s1;
    redsq[rq][uc * 2] = ss0;   redsq[rq][uc * 2 + 1] = ss1;
    __syncthreads();
    int t = threadIdx.x;
    if (t < 128) {
        st_dev(&psum[blockIdx.x * 128 + t], red[0][t] + red[1][t] + red[2][t] + red[3][t]);
    } else {
        int c = t - 128;
        st_dev(&psumsq[blockIdx.x * 128 + c], redsq[0][c] + redsq[1][c] + redsq[2][c] + redsq[3][c]);
    }
    __syncthreads();   // drains vmcnt(0): all st_dev complete before counter bump
    __shared__ int isLast;
    if (t == 0) isLast = (atomicAdd(counter, 1) == (int)gridDim.x - 1);
    __syncthreads();
    if (!isLast) return;
    __threadfence();   // single acquire fence, last block only
    if (t < 128) {
        float s = 0.f, ss = 0.f;
        for (int b = 0; b < BN_NB; ++b) {
            s += ld_dev(&psum[b * 128 + t]);
            ss += ld_dev(&psumsq[b * 128 + t]);
        }
        const float inv = 1.f / NNODES;
        float mu = s * inv;
        float var = ss * inv - mu * mu;
        float sc = g[t] * rsqrtf(var + BN_EPS);
        scale[t] = sc;
        shift[t] = beta[t] - mu * sc;
    }
}

// ==================== gather H=1 with fused graph pooling ====================
__global__ __launch_bounds__(256) void gat_gather1_kernel(
        const int* __restrict__ rowptr, const int* __restrict__ csr_src,
        const float* __restrict__ el, const float* __restrict__ er,
        const ushort* __restrict__ feat, const float* __restrict__ bias,
        const int* __restrict__ gid, float* __restrict__ pooled) {
    const int d = __builtin_amdgcn_readfirstlane(
        (int)((blockIdx.x * blockDim.x + threadIdx.x) >> 6));
    int lane = threadIdx.x & 63;
    if (d >= NNODES) return;
    const int r0 = rowptr[d];
    const int deg = rowptr[d + 1] - r0;
    const int half = lane >> 5;
    const int c    = lane & 31;
    const float erh = er[d];
    float dnm = 0.f, acc = 0.f;

    for (int j0 = 0; j0 < deg; j0 += 32) {
        int eidx = j0 + (lane & 31);
        int s_e = 0;
        float ex = 0.f;
        if (eidx < deg) {
            s_e = csr_src[r0 + eidx];
            float v = el[s_e] + erh;
            v = v > 0.f ? v : NEG_SLOPE * v;
            ex = __expf(v);
        }
        dnm += ex;
        ushort u[16];
#pragma unroll
        for (int jj = 0; jj < 16; ++jj) {
            int sj = __shfl(s_e, 2 * jj + half);
            u[jj] = feat[(size_t)sj * 32 + c];
        }
#pragma unroll
        for (int jj = 0; jj < 16; ++jj) {
            float exj = __shfl(ex, 2 * jj + half);
            acc = fmaf(exj, bf2f(u[jj]), acc);
        }
    }
#pragma unroll
    for (int off = 1; off < 32; off <<= 1) dnm += __shfl_xor(dnm, off);
    acc += __shfl_down(acc, 32);
    if (half == 0) {
        float inv = (dnm > 0.f) ? 1.f / dnm : 0.f;
        atomicAdd(&pooled[gid[d] * 32 + c], acc * inv + bias[c]);
    }
}

// ---- classifier (separate tiny launch — fusing it cost 240 µs, see round 2) ----
__global__ void classify_kernel(const float* __restrict__ pooled, const float* __restrict__ Wc,
                                const float* __restrict__ bc, float* __restrict__ out) {
    int t = blockIdx.x * blockDim.x + threadIdx.x;
    if (t >= NGRAPHS * 10) return;
    int gIdx = t / 10, j = t % 10;
    float s = bc[j];
#pragma unroll
    for (int c = 0; c < 32; ++c) s += pooled[gIdx * 32 + c] * Wc[c * 10 + j];
    out[t] = s;
}

extern "C" void kernel_launch(void* const* d_in, const int* in_sizes, int n_in,
                              void* d_out, int out_size, void* d_ws, size_t ws_size,
                              hipStream_t stream) {
    const float* x     = (const float*)d_in[0];
    const int*   esrc  = (const int*)d_in[1];
    const int*   edst  = (const int*)d_in[2];
    const int*   gid   = (const int*)d_in[3];
    const float* W0    = (const float*)d_in[4];
    const float* al0   = (const float*)d_in[5];
    const float* ar0   = (const float*)d_in[6];
    const float* b0    = (const float*)d_in[7];
    const float* W1    = (const float*)d_in[8];
    const float* al1   = (const float*)d_in[9];
    const float* ar1   = (const float*)d_in[10];
    const float* b1    = (const float*)d_in[11];
    const float* W2    = (const float*)d_in[12];
    const float* al2   = (const float*)d_in[13];
    const float* ar2   = (const float*)d_in[14];
    const float* b2    = (const float*)d_in[15];
    const float* g0    = (const float*)d_in[16];
    const float* beta0 = (const float*)d_in[17];
    const float* g1    = (const float*)d_in[18];
    const float* beta1 = (const float*)d_in[19];
    const float* Wc    = (const float*)d_in[20];
    const float* bc    = (const float*)d_in[21];

    // ---- workspace layout: one contiguous zero-init region first ----
    int*   counters = (int*)d_ws;                             // [8]: 0=bn0 1=bn1
    int*   rhist    = counters + 8;                           // [196]
    int*   rcursor  = rhist + NRANGE;                         // [196]
    float* pooled   = (float*)(rcursor + NRANGE);             // [500*32]
    float* psum     = pooled + NGRAPHS * 32;                  // [400*128]
    float* psumsq   = psum + BN_NB * 128;                     // [400*128]
    float* scale0   = psumsq + BN_NB * 128;                   // [128]
    float* shift0   = scale0 + 128;
    float* scale1   = shift0 + 128;
    float* shift1   = scale1 + 128;
    int*   rowptr   = (int*)(shift1 + 128);                   // [N+1]
    int*   csr_src  = rowptr + NNODES + 1;                    // [E]
    uint*  bucket   = (uint*)(csr_src + NEDGES);              // [E]
    size_t ofs = (size_t)((int*)(bucket + NEDGES) - (int*)d_ws);
    ofs = (ofs + 3) & ~(size_t)3;                             // 16B alignment
    ushort* featbf = (ushort*)((int*)d_ws + ofs);             // [N,128] bf16 GEMM out
    ushort* xnext  = featbf + (size_t)NNODES * 128;           // [N,128] bf16 gather out / GEMM in
    float*  el     = (float*)(xnext + (size_t)NNODES * 128);  // [N,4]
    float*  er     = el + (size_t)NNODES * 4;                 // [N,4]
    ushort* Wt0    = (ushort*)(er + (size_t)NNODES * 4);      // [128,128]
    ushort* Wt1    = Wt0 + 128 * 128;                         // [128,128]
    ushort* Wt2    = Wt1 + 128 * 128;                         // [32,128]

    const int T = 256;
    float* out = (float*)d_out;

    const int GATHER_BLOCKS  = (NNODES * 64) / T;             // exact: 12500
    const int GEMM128_BLOCKS = (NNODES + 63) / 64;            // 782
    const int GEMM32_BLOCKS  = (NNODES + 127) / 128;          // 391

    // ---- single zero-init (counters + rhist + rcursor + pooled) ----
    hipMemsetAsync(counters, 0, (size_t)(8 + NRANGE + NRANGE + NGRAPHS * 32) * 4, stream);
    prep_hist_kernel<<<RH_NB, T, 0, stream>>>(W0, W1, W2, Wt0, Wt1, Wt2, edst, rhist, rowptr);
    reorder_kernel<<<RH_NB, T, 0, stream>>>(esrc, edst, rhist, rcursor, bucket);

    // ================= Layer 0 GEMM fused with CSR finalize (independent roles) ======
    csr_gemm0_kernel<<<NRANGE + GEMM128_BLOCKS, T, 0, stream>>>(
        rhist, bucket, rowptr, csr_src, x, Wt0, al0, ar0, featbf, el, er);
    gat_gather4_kernel<<<GATHER_BLOCKS, T, 0, stream>>>(rowptr, csr_src, el, er, featbf, b0, xnext);
    bn_stats_kernel<<<BN_NB, T, 0, stream>>>(xnext, psum, psumsq, g0, beta0, scale0, shift0,
                                             &counters[0]);

    // ================= Layer 1 =================
    gemm_mfma_kernel<128, true><<<GEMM128_BLOCKS, T, 0, stream>>>(
        xnext, Wt1, scale0, shift0, al1, ar1, featbf, el, er, NNODES);
    gat_gather4_kernel<<<GATHER_BLOCKS, T, 0, stream>>>(rowptr, csr_src, el, er, featbf, b1, xnext);
    bn_stats_kernel<<<BN_NB, T, 0, stream>>>(xnext, psum, psumsq, g1, beta1, scale1, shift1,
                                             &counters[1]);

    // ================= Layer 2 (H=1, D=32) =================
    gemm_mfma_kernel<32, true><<<GEMM32_BLOCKS, T, 0, stream>>>(
        xnext, Wt2, scale1, shift1, al2, ar2, featbf, el, er, NNODES);
    gat_gather1_kernel<<<GATHER_BLOCKS, T, 0, stream>>>(rowptr, csr_src, el, er, featbf, b2,
                                                        gid, pooled);

    // ================= Classify =================
    classify_kernel<<<(NGRAPHS * 10 + T - 1) / T, T, 0, stream>>>(pooled, Wc, bc, out);
}

// Round 7
// 348.753 us; speedup vs baseline: 2.5782x; 1.0202x over previous
//
#include <hip/hip_runtime.h>
#include <math.h>

#define NNODES 50000
#define NEDGES 800000
#define NGRAPHS 500
#define NEG_SLOPE 0.2f
#define BN_EPS 1e-5f
#define NRANGE 196            // ceil(50000/256) node ranges of 256
#define RH_EPB 2048           // edges per block in range hist/reorder (391 blocks)
#define RH_NB ((NEDGES + RH_EPB - 1) / RH_EPB)
#define MAXRE 5120            // LDS stage capacity per range
#define BN_NB 400
#define BN_RPB 125

typedef unsigned int uint;
typedef unsigned short ushort;
typedef __attribute__((ext_vector_type(8))) short bf16x8;
typedef __attribute__((ext_vector_type(4))) float f32x4;

// ---- bf16 helpers (storage-only bf16; math fp32 / MFMA fp32-acc) ----
__device__ __forceinline__ float bf2f(ushort u) { return __uint_as_float(((uint)u) << 16); }
__device__ __forceinline__ float bflo(uint u)   { return __uint_as_float(u << 16); }
__device__ __forceinline__ float bfhi(uint u)   { return __uint_as_float(u & 0xffff0000u); }
__device__ __forceinline__ ushort f2bf(float f) {
    uint u = __float_as_uint(f);
    u = (u + 0x7fffu + ((u >> 16) & 1u)) >> 16;   // RNE
    return (ushort)u;
}

// agent-scope (device) coherent load/store
__device__ __forceinline__ float ld_dev(const float* p) {
    return __hip_atomic_load(p, __ATOMIC_RELAXED, __HIP_MEMORY_SCOPE_AGENT);
}
__device__ __forceinline__ void st_dev(float* p, float v) {
    __hip_atomic_store(p, v, __ATOMIC_RELAXED, __HIP_MEMORY_SCOPE_AGENT);
}

// ---- prep (weight convert/transpose) FUSED with range histogram ----
__global__ __launch_bounds__(256) void prep_hist_kernel(
        const float* __restrict__ W0, const float* __restrict__ W1,
        const float* __restrict__ W2, ushort* __restrict__ Wt0,
        ushort* __restrict__ Wt1, ushort* __restrict__ Wt2,
        const int* __restrict__ dst, int* __restrict__ rhist,
        int* __restrict__ rowptr) {
    int t = blockIdx.x * 256 + threadIdx.x;
    if (t == 0) rowptr[NNODES] = NEDGES;
    if (t < 16384) {                       // W0 [128][128]
        int k = t >> 7, m = t & 127;
        Wt0[m * 128 + k] = f2bf(W0[t]);
    } else if (t < 32768) {                // W1 [128][128]
        int i = t - 16384;
        int k = i >> 7, m = i & 127;
        Wt1[m * 128 + k] = f2bf(W1[i]);
    } else if (t < 36864) {                // W2 [128][32]
        int i = t - 32768;
        int k = i >> 5, m = i & 31;
        Wt2[m * 128 + k] = f2bf(W2[i]);
    }
    __shared__ int cnt[NRANGE];
    for (int i = threadIdx.x; i < NRANGE; i += 256) cnt[i] = 0;
    __syncthreads();
    int base = blockIdx.x * RH_EPB;
    int end = base + RH_EPB; if (end > NEDGES) end = NEDGES;
    for (int i = base + threadIdx.x; i < end; i += 256) atomicAdd(&cnt[dst[i] >> 8], 1);
    __syncthreads();
    for (int i = threadIdx.x; i < NRANGE; i += 256)
        if (cnt[i]) atomicAdd(&rhist[i], cnt[i]);
}

// ==================== reorder (scan fused redundantly per block) ====================
__global__ __launch_bounds__(256) void reorder_kernel(
        const int* __restrict__ src, const int* __restrict__ dst,
        const int* __restrict__ rhist, int* __restrict__ rcursor,
        uint* __restrict__ bucket) {
    __shared__ int cnt[NRANGE];
    __shared__ int bofs[NRANGE];
    __shared__ int rb[256];            // inclusive scan of rhist
    const int t = threadIdx.x;
    rb[t] = (t < NRANGE) ? rhist[t] : 0;
    if (t < NRANGE) cnt[t] = 0;
    __syncthreads();
    for (int off = 1; off < 256; off <<= 1) {
        int u = (t >= off) ? rb[t - off] : 0;
        __syncthreads();
        rb[t] += u;
        __syncthreads();
    }
    int base = blockIdx.x * RH_EPB;
    int end = base + RH_EPB; if (end > NEDGES) end = NEDGES;
    for (int i = base + t; i < end; i += 256) atomicAdd(&cnt[dst[i] >> 8], 1);
    __syncthreads();
    for (int i = t; i < NRANGE; i += 256) {
        int c = cnt[i];
        int ex = (i == 0) ? 0 : rb[i - 1];           // exclusive range base
        bofs[i] = c ? (ex + atomicAdd(&rcursor[i], c)) : 0;
    }
    __syncthreads();
    for (int i = t; i < NRANGE; i += 256) cnt[i] = 0;
    __syncthreads();
    for (int i = base + t; i < end; i += 256) {
        int d = dst[i], r = d >> 8;
        int loc = atomicAdd(&cnt[r], 1);
        bucket[bofs[r] + loc] = (uint)src[i] | ((uint)(d & 255) << 16);
    }
}

// ==================== FUSED: range CSR build (blocks 0..195) + GEMM layer0 (rest) ====
__global__ __launch_bounds__(256) void csr_gemm0_kernel(
        const int* __restrict__ rhist, const uint* __restrict__ bucket,
        int* __restrict__ rowptr, int* __restrict__ csr_src,
        const float* __restrict__ X, const ushort* __restrict__ Wt,
        const float* __restrict__ al, const float* __restrict__ ar,
        ushort* __restrict__ Y, float* __restrict__ el, float* __restrict__ er) {
    __shared__ union {
        struct { uint ebuf[MAXRE]; int deg[256]; int excl[256]; int cur[256]; int rb[256]; } c;
        struct { ushort xs[64][136]; } g;
    } sh;
    const int t = threadIdx.x;

    if (blockIdx.x < NRANGE) {
        // ---------------- CSR role ----------------
        const int r = blockIdx.x;
        sh.c.rb[t] = (t < NRANGE) ? rhist[t] : 0;
        __syncthreads();
        for (int off = 1; off < 256; off <<= 1) {
            int u = (t >= off) ? sh.c.rb[t - off] : 0;
            __syncthreads();
            sh.c.rb[t] += u;
            __syncthreads();
        }
        const int b0 = (r == 0) ? 0 : sh.c.rb[r - 1];
        const int cnt = sh.c.rb[r] - b0;
        sh.c.deg[t] = 0; sh.c.cur[t] = 0;
        __syncthreads();
        for (int i = t; i < cnt; i += 256) {
            uint e = bucket[b0 + i];
            sh.c.ebuf[i] = e;
            atomicAdd(&sh.c.deg[e >> 16], 1);
        }
        __syncthreads();
        sh.c.excl[t] = sh.c.deg[t];
        __syncthreads();
        for (int off = 1; off < 256; off <<= 1) {
            int u = (t >= off) ? sh.c.excl[t - off] : 0;
            __syncthreads();
            sh.c.excl[t] += u;
            __syncthreads();
        }
        int myExcl = (t == 0) ? 0 : sh.c.excl[t - 1];
        __syncthreads();
        sh.c.excl[t] = myExcl;
        __syncthreads();
        int node = r * 256 + t;
        if (node < NNODES) rowptr[node] = b0 + myExcl;
        for (int i = t; i < cnt; i += 256) {
            uint e = sh.c.ebuf[i];
            int dl = e >> 16;
            int loc = atomicAdd(&sh.c.cur[dl], 1);
            csr_src[b0 + sh.c.excl[dl] + loc] = (int)(e & 0xffffu);
        }
        return;
    }

    // ---------------- GEMM role (M=128, fp32 input, no BN) ----------------
    const int wv = t >> 6, lane = t & 63;
    const int rowBase = (int)(blockIdx.x - NRANGE) * 64;
    const int N = NNODES;

    for (int i = t; i < 64 * 32; i += 256) {
        int rr = i >> 5, c4 = i & 31;
        int gr = rowBase + rr;
        float4 v = make_float4(0.f, 0.f, 0.f, 0.f);
        if (gr < N) v = *(const float4*)(X + (size_t)gr * 128 + c4 * 4);
        ushort* o = &sh.g.xs[rr][c4 * 4];
        o[0] = f2bf(v.x); o[1] = f2bf(v.y); o[2] = f2bf(v.z); o[3] = f2bf(v.w);
    }
    __syncthreads();

    const int waveCol = wv * 32;
    const int fr = lane & 15, quad = lane >> 4;

    f32x4 acc[4][2];
#pragma unroll
    for (int rt = 0; rt < 4; ++rt)
#pragma unroll
        for (int ct = 0; ct < 2; ++ct) acc[rt][ct] = (f32x4){0.f, 0.f, 0.f, 0.f};

#pragma unroll
    for (int ks = 0; ks < 4; ++ks) {
        const int kb = ks * 32 + quad * 8;
        bf16x8 a[4], b[2];
#pragma unroll
        for (int rt = 0; rt < 4; ++rt) a[rt] = *(const bf16x8*)&sh.g.xs[rt * 16 + fr][kb];
#pragma unroll
        for (int ct = 0; ct < 2; ++ct)
            b[ct] = *(const bf16x8*)(Wt + (size_t)(waveCol + ct * 16 + fr) * 128 + kb);
#pragma unroll
        for (int rt = 0; rt < 4; ++rt)
#pragma unroll
            for (int ct = 0; ct < 2; ++ct)
                acc[rt][ct] = __builtin_amdgcn_mfma_f32_16x16x32_bf16(a[rt], b[ct], acc[rt][ct], 0, 0, 0);
    }

    // fused el/er epilogue
    const float a0 = al[waveCol + fr],      a1 = al[waveCol + 16 + fr];
    const float g0 = ar[waveCol + fr],      g1 = ar[waveCol + 16 + fr];
    const int h = wv;
#pragma unroll
    for (int rt = 0; rt < 4; ++rt)
#pragma unroll
        for (int rg = 0; rg < 4; ++rg) {
            float pe = acc[rt][0][rg] * a0 + acc[rt][1][rg] * a1;
            float pr = acc[rt][0][rg] * g0 + acc[rt][1][rg] * g1;
#pragma unroll
            for (int off = 1; off < 16; off <<= 1) {
                pe += __shfl_xor(pe, off);
                pr += __shfl_xor(pr, off);
            }
            int grow = rowBase + rt * 16 + quad * 4 + rg;
            if (fr == 0 && grow < N) {
                el[grow * 4 + h] = pe;
                er[grow * 4 + h] = pr;
            }
        }

    // coalesced Y store via LDS transpose (reuse xs)
    __syncthreads();
#pragma unroll
    for (int rt = 0; rt < 4; ++rt)
#pragma unroll
        for (int ct = 0; ct < 2; ++ct)
#pragma unroll
            for (int rg = 0; rg < 4; ++rg) {
                int lr = rt * 16 + quad * 4 + rg;
                int lc = waveCol + ct * 16 + fr;
                sh.g.xs[lr][lc] = f2bf(acc[rt][ct][rg]);
            }
    __syncthreads();
    {
        int row = t >> 2, seg = t & 3;
        int gr = rowBase + row;
        if (gr < N) {
#pragma unroll
            for (int q = 0; q < 4; ++q) {
                int col = (seg * 4 + q) * 8;
                *(uint4*)(Y + (size_t)gr * 128 + col) = *(const uint4*)&sh.g.xs[row][col];
            }
        }
    }
}

// ==================== MFMA bf16 GEMM, fused BN/ReLU input + el/er epilogue ====================
template <int M, bool HASBN>
__global__ __launch_bounds__(256) void gemm_mfma_kernel(
        const void* __restrict__ Xv, const ushort* __restrict__ Wt,
        const float* __restrict__ scale, const float* __restrict__ shift,
        const float* __restrict__ al, const float* __restrict__ ar,
        ushort* __restrict__ Y, float* __restrict__ el, float* __restrict__ er, int N) {
    constexpr int H   = M / 32;
    constexpr int BR  = (M == 128) ? 64 : 128;
    constexpr int RT  = (M == 128) ? 4 : 2;
    constexpr int CT  = 2;
    constexpr int LDK = 136;
    __shared__ ushort xs[BR][LDK];
    __shared__ float scs[128], shs[128];

    const int tid = threadIdx.x, wv = tid >> 6, lane = tid & 63;
    const int rowBase = blockIdx.x * BR;

    if (HASBN) {
        if (tid < 128) {
            scs[tid] = scale[tid];
            shs[tid] = shift[tid];
        }
        __syncthreads();
    }

    if (HASBN) {
        const ushort* X = (const ushort*)Xv;
        for (int i = tid; i < BR * 16; i += 256) {
            int rr = i >> 4, q = i & 15;
            int gr = rowBase + rr;
            uint4 u = make_uint4(0, 0, 0, 0);
            if (gr < N) u = *(const uint4*)(X + (size_t)gr * 128 + q * 8);
            uint arr[4] = {u.x, u.y, u.z, u.w};
            ushort* o = &xs[rr][q * 8];
#pragma unroll
            for (int j = 0; j < 4; ++j) {
                int c = q * 8 + j * 2;
                float lo = fmaxf(bflo(arr[j]) * scs[c] + shs[c], 0.f);
                float hi = fmaxf(bfhi(arr[j]) * scs[c + 1] + shs[c + 1], 0.f);
                o[j * 2]     = f2bf(lo);
                o[j * 2 + 1] = f2bf(hi);
            }
        }
    } else {
        const float* X = (const float*)Xv;
        for (int i = tid; i < BR * 32; i += 256) {
            int rr = i >> 5, c4 = i & 31;
            int gr = rowBase + rr;
            float4 v = make_float4(0.f, 0.f, 0.f, 0.f);
            if (gr < N) v = *(const float4*)(X + (size_t)gr * 128 + c4 * 4);
            ushort* o = &xs[rr][c4 * 4];
            o[0] = f2bf(v.x); o[1] = f2bf(v.y); o[2] = f2bf(v.z); o[3] = f2bf(v.w);
        }
    }
    __syncthreads();

    const int waveRow = (M == 128) ? 0 : (wv * 32);
    const int waveCol = (M == 128) ? (wv * 32) : 0;
    const int fr = lane & 15, quad = lane >> 4;

    f32x4 acc[RT][CT];
#pragma unroll
    for (int rt = 0; rt < RT; ++rt)
#pragma unroll
        for (int ct = 0; ct < CT; ++ct) acc[rt][ct] = (f32x4){0.f, 0.f, 0.f, 0.f};

#pragma unroll
    for (int ks = 0; ks < 4; ++ks) {
        const int kb = ks * 32 + quad * 8;
        bf16x8 a[RT], b[CT];
#pragma unroll
        for (int rt = 0; rt < RT; ++rt) a[rt] = *(const bf16x8*)&xs[waveRow + rt * 16 + fr][kb];
#pragma unroll
        for (int ct = 0; ct < CT; ++ct)
            b[ct] = *(const bf16x8*)(Wt + (size_t)(waveCol + ct * 16 + fr) * 128 + kb);
#pragma unroll
        for (int rt = 0; rt < RT; ++rt)
#pragma unroll
            for (int ct = 0; ct < CT; ++ct)
                acc[rt][ct] = __builtin_amdgcn_mfma_f32_16x16x32_bf16(a[rt], b[ct], acc[rt][ct], 0, 0, 0);
    }

    // fused el/er epilogue
    const float a0 = al[waveCol + fr],      a1 = al[waveCol + 16 + fr];
    const float g0 = ar[waveCol + fr],      g1 = ar[waveCol + 16 + fr];
    const int h = (M == 128) ? wv : 0;
#pragma unroll
    for (int rt = 0; rt < RT; ++rt)
#pragma unroll
        for (int rg = 0; rg < 4; ++rg) {
            float pe = acc[rt][0][rg] * a0 + acc[rt][1][rg] * a1;
            float pr = acc[rt][0][rg] * g0 + acc[rt][1][rg] * g1;
#pragma unroll
            for (int off = 1; off < 16; off <<= 1) {
                pe += __shfl_xor(pe, off);
                pr += __shfl_xor(pr, off);
            }
            int grow = rowBase + waveRow + rt * 16 + quad * 4 + rg;
            if (fr == 0 && grow < N) {
                el[grow * H + h] = pe;
                er[grow * H + h] = pr;
            }
        }

    // ---- coalesced Y store via LDS transpose (reuse xs) ----
    __syncthreads();
#pragma unroll
    for (int rt = 0; rt < RT; ++rt)
#pragma unroll
        for (int ct = 0; ct < CT; ++ct)
#pragma unroll
            for (int rg = 0; rg < 4; ++rg) {
                int lr = waveRow + rt * 16 + quad * 4 + rg;
                int lc = waveCol + ct * 16 + fr;
                xs[lr][lc] = f2bf(acc[rt][ct][rg]);
            }
    __syncthreads();
    if (M == 128) {
        int row = tid >> 2, seg = tid & 3;
        int gr = rowBase + row;
        if (gr < N) {
#pragma unroll
            for (int q = 0; q < 4; ++q) {
                int col = (seg * 4 + q) * 8;
                *(uint4*)(Y + (size_t)gr * 128 + col) = *(const uint4*)&xs[row][col];
            }
        }
    } else {
        int row = tid >> 1, hf = tid & 1;
        int gr = rowBase + row;
        if (gr < N) {
#pragma unroll
            for (int q = 0; q < 2; ++q) {
                int col = (hf * 2 + q) * 8;
                *(uint4*)(Y + (size_t)gr * 32 + col) = *(const uint4*)&xs[row][col];
            }
        }
    }
}

// ==================== gather H=4: TWO nodes per wave, phase-interleaved ===============
// MLP experiment: both nodes' csr/el/exp issue together, then 32 feat rows (16+16)
// are in flight before either MAC phase. Doubles per-wave outstanding loads in the
// dominant deg<=16 case (where chunk-level ping-pong never engaged). 25000 waves.
__global__ __launch_bounds__(256) void gat_gather4_kernel(
        const int* __restrict__ rowptr, const int* __restrict__ csr_src,
        const float* __restrict__ el, const float* __restrict__ er,
        const ushort* __restrict__ feat, const float* __restrict__ bias,
        ushort* __restrict__ xnext) {
    const int d0 = __builtin_amdgcn_readfirstlane(
        (int)(((blockIdx.x * blockDim.x + threadIdx.x) >> 6) * 2));
    const int lane = threadIdx.x & 63;
    if (d0 >= NNODES) return;
    const int h   = lane >> 4;
    const int k   = lane & 15;
    const int grp = lane & 48;
    const int c0  = lane * 2;
    // adjacent CSR rows: [r0a, r0b) and [r0b, rEnd)
    const int r0a  = rowptr[d0];
    const int r0b  = rowptr[d0 + 1];
    const int rEnd = rowptr[d0 + 2];
    const int degA = r0b - r0a;
    const int degB = rEnd - r0b;
    const float erhA = er[d0 * 4 + h];
    const float erhB = er[(d0 + 1) * 4 + h];
    float dnmA = 0.f, axA = 0.f, ayA = 0.f;
    float dnmB = 0.f, axB = 0.f, ayB = 0.f;

    const int degM = degA > degB ? degA : degB;
    for (int j0 = 0; j0 < degM; j0 += 16) {
        const bool hasA = j0 < degA, hasB = j0 < degB;   // wave-uniform
        const int ia = j0 + k;
        int sA = 0, sB = 0;
        float exA = 0.f, exB = 0.f;
        if (ia < degA) sA = csr_src[r0a + ia];           // both index loads issue first
        if (ia < degB) sB = csr_src[r0b + ia];
        if (ia < degA) {
            float v = el[sA * 4 + h] + erhA;
            v = v > 0.f ? v : NEG_SLOPE * v;
            exA = __expf(v);
        }
        if (ia < degB) {
            float v = el[sB * 4 + h] + erhB;
            v = v > 0.f ? v : NEG_SLOPE * v;
            exB = __expf(v);
        }
        dnmA += exA; dnmB += exB;
        uint uA[16], uB[16];
        if (hasA) {                                      // 16 rows node A in flight
#pragma unroll
            for (int jj = 0; jj < 16; ++jj) {
                int sj = __builtin_amdgcn_readlane(sA, jj);
                uA[jj] = *(const uint*)(feat + (size_t)sj * 128 + c0);
            }
        }
        if (hasB) {                                      // +16 rows node B in flight
#pragma unroll
            for (int jj = 0; jj < 16; ++jj) {
                int sj = __builtin_amdgcn_readlane(sB, jj);
                uB[jj] = *(const uint*)(feat + (size_t)sj * 128 + c0);
            }
        }
        if (hasA) {                                      // MAC A under B's latency
#pragma unroll
            for (int jj = 0; jj < 16; ++jj) {
                float e = __shfl(exA, grp + jj);
                axA = fmaf(e, bflo(uA[jj]), axA);
                ayA = fmaf(e, bfhi(uA[jj]), ayA);
            }
        }
        if (hasB) {
#pragma unroll
            for (int jj = 0; jj < 16; ++jj) {
                float e = __shfl(exB, grp + jj);
                axB = fmaf(e, bflo(uB[jj]), axB);
                ayB = fmaf(e, bfhi(uB[jj]), ayB);
            }
        }
    }
#pragma unroll
    for (int off = 1; off < 16; off <<= 1) {
        dnmA += __shfl_xor(dnmA, off);
        dnmB += __shfl_xor(dnmB, off);
    }
    const float bz0 = bias[c0], bz1 = bias[c0 + 1];
    float invA = (dnmA > 0.f) ? 1.f / dnmA : 0.f;
    float invB = (dnmB > 0.f) ? 1.f / dnmB : 0.f;
    uint pkA = ((uint)f2bf(ayA * invA + bz1) << 16) | (uint)f2bf(axA * invA + bz0);
    uint pkB = ((uint)f2bf(ayB * invB + bz1) << 16) | (uint)f2bf(axB * invB + bz0);
    *(uint*)(xnext + (size_t)d0 * 128 + c0) = pkA;
    *(uint*)(xnext + (size_t)(d0 + 1) * 128 + c0) = pkB;
}

// ---- BN stats + FUSED finalize (last-block-done; 400 blocks; no per-block fence) ----
__global__ __launch_bounds__(256) void bn_stats_kernel(
        const ushort* __restrict__ X, float* __restrict__ psum, float* __restrict__ psumsq,
        const float* __restrict__ g, const float* __restrict__ beta,
        float* __restrict__ scale, float* __restrict__ shift, int* __restrict__ counter) {
    const uint* X32 = (const uint*)X;          // [N][64] packed col pairs
    int uc = threadIdx.x & 63;                 // uint col (cols 2uc, 2uc+1)
    int rq = threadIdx.x >> 6;                 // row quarter
    int r0 = blockIdx.x * BN_RPB;
    float s0 = 0.f, s1 = 0.f, ss0 = 0.f, ss1 = 0.f;
    for (int r = r0 + rq; r < r0 + BN_RPB; r += 4) {
        uint u = X32[(size_t)r * 64 + uc];
        float lo = bflo(u), hi = bfhi(u);
        s0 += lo; ss0 += lo * lo;
        s1 += hi; ss1 += hi * hi;
    }
    __shared__ float red[4][256], redsq[4][256];
    red[rq][uc * 2] = s0;      red[rq][uc * 2 + 1] = s1;
    redsq[rq][uc * 2] = ss0;   redsq[rq][uc * 2 + 1] = ss1;
    __syncthreads();
    int t = threadIdx.x;
    if (t < 128) {
        st_dev(&psum[blockIdx.x * 128 + t], red[0][t] + red[1][t] + red[2][t] + red[3][t]);
    } else {
        int c = t - 128;
        st_dev(&psumsq[blockIdx.x * 128 + c], redsq[0][c] + redsq[1][c] + redsq[2][c] + redsq[3][c]);
    }
    __syncthreads();   // drains vmcnt(0): all st_dev complete before counter bump
    __shared__ int isLast;
    if (t == 0) isLast = (atomicAdd(counter, 1) == (int)gridDim.x - 1);
    __syncthreads();
    if (!isLast) return;
    __threadfence();   // single acquire fence, last block only
    if (t < 128) {
        float s = 0.f, ss = 0.f;
        for (int b = 0; b < BN_NB; ++b) {
            s += ld_dev(&psum[b * 128 + t]);
            ss += ld_dev(&psumsq[b * 128 + t]);
        }
        const float inv = 1.f / NNODES;
        float mu = s * inv;
        float var = ss * inv - mu * mu;
        float sc = g[t] * rsqrtf(var + BN_EPS);
        scale[t] = sc;
        shift[t] = beta[t] - mu * sc;
    }
}

// ==================== gather H=1 with fused graph pooling ====================
__global__ __launch_bounds__(256) void gat_gather1_kernel(
        const int* __restrict__ rowptr, const int* __restrict__ csr_src,
        const float* __restrict__ el, const float* __restrict__ er,
        const ushort* __restrict__ feat, const float* __restrict__ bias,
        const int* __restrict__ gid, float* __restrict__ pooled) {
    const int d = __builtin_amdgcn_readfirstlane(
        (int)((blockIdx.x * blockDim.x + threadIdx.x) >> 6));
    int lane = threadIdx.x & 63;
    if (d >= NNODES) return;
    const int r0 = rowptr[d];
    const int deg = rowptr[d + 1] - r0;
    const int half = lane >> 5;
    const int c    = lane & 31;
    const float erh = er[d];
    float dnm = 0.f, acc = 0.f;

    for (int j0 = 0; j0 < deg; j0 += 32) {
        int eidx = j0 + (lane & 31);
        int s_e = 0;
        float ex = 0.f;
        if (eidx < deg) {
            s_e = csr_src[r0 + eidx];
            float v = el[s_e] + erh;
            v = v > 0.f ? v : NEG_SLOPE * v;
            ex = __expf(v);
        }
        dnm += ex;
        ushort u[16];
#pragma unroll
        for (int jj = 0; jj < 16; ++jj) {
            int sj = __shfl(s_e, 2 * jj + half);
            u[jj] = feat[(size_t)sj * 32 + c];
        }
#pragma unroll
        for (int jj = 0; jj < 16; ++jj) {
            float exj = __shfl(ex, 2 * jj + half);
            acc = fmaf(exj, bf2f(u[jj]), acc);
        }
    }
#pragma unroll
    for (int off = 1; off < 32; off <<= 1) dnm += __shfl_xor(dnm, off);
    acc += __shfl_down(acc, 32);
    if (half == 0) {
        float inv = (dnm > 0.f) ? 1.f / dnm : 0.f;
        atomicAdd(&pooled[gid[d] * 32 + c], acc * inv + bias[c]);
    }
}

// ---- classifier (separate tiny launch — fusing it cost 240 µs, see round 2) ----
__global__ void classify_kernel(const float* __restrict__ pooled, const float* __restrict__ Wc,
                                const float* __restrict__ bc, float* __restrict__ out) {
    int t = blockIdx.x * blockDim.x + threadIdx.x;
    if (t >= NGRAPHS * 10) return;
    int gIdx = t / 10, j = t % 10;
    float s = bc[j];
#pragma unroll
    for (int c = 0; c < 32; ++c) s += pooled[gIdx * 32 + c] * Wc[c * 10 + j];
    out[t] = s;
}

extern "C" void kernel_launch(void* const* d_in, const int* in_sizes, int n_in,
                              void* d_out, int out_size, void* d_ws, size_t ws_size,
                              hipStream_t stream) {
    const float* x     = (const float*)d_in[0];
    const int*   esrc  = (const int*)d_in[1];
    const int*   edst  = (const int*)d_in[2];
    const int*   gid   = (const int*)d_in[3];
    const float* W0    = (const float*)d_in[4];
    const float* al0   = (const float*)d_in[5];
    const float* ar0   = (const float*)d_in[6];
    const float* b0    = (const float*)d_in[7];
    const float* W1    = (const float*)d_in[8];
    const float* al1   = (const float*)d_in[9];
    const float* ar1   = (const float*)d_in[10];
    const float* b1    = (const float*)d_in[11];
    const float* W2    = (const float*)d_in[12];
    const float* al2   = (const float*)d_in[13];
    const float* ar2   = (const float*)d_in[14];
    const float* b2    = (const float*)d_in[15];
    const float* g0    = (const float*)d_in[16];
    const float* beta0 = (const float*)d_in[17];
    const float* g1    = (const float*)d_in[18];
    const float* beta1 = (const float*)d_in[19];
    const float* Wc    = (const float*)d_in[20];
    const float* bc    = (const float*)d_in[21];

    // ---- workspace layout: one contiguous zero-init region first ----
    int*   counters = (int*)d_ws;                             // [8]: 0=bn0 1=bn1
    int*   rhist    = counters + 8;                           // [196]
    int*   rcursor  = rhist + NRANGE;                         // [196]
    float* pooled   = (float*)(rcursor + NRANGE);             // [500*32]
    float* psum     = pooled + NGRAPHS * 32;                  // [400*128]
    float* psumsq   = psum + BN_NB * 128;                     // [400*128]
    float* scale0   = psumsq + BN_NB * 128;                   // [128]
    float* shift0   = scale0 + 128;
    float* scale1   = shift0 + 128;
    float* shift1   = scale1 + 128;
    int*   rowptr   = (int*)(shift1 + 128);                   // [N+1]
    int*   csr_src  = rowptr + NNODES + 1;                    // [E]
    uint*  bucket   = (uint*)(csr_src + NEDGES);              // [E]
    size_t ofs = (size_t)((int*)(bucket + NEDGES) - (int*)d_ws);
    ofs = (ofs + 3) & ~(size_t)3;                             // 16B alignment
    ushort* featbf = (ushort*)((int*)d_ws + ofs);             // [N,128] bf16 GEMM out
    ushort* xnext  = featbf + (size_t)NNODES * 128;           // [N,128] bf16 gather out / GEMM in
    float*  el     = (float*)(xnext + (size_t)NNODES * 128);  // [N,4]
    float*  er     = el + (size_t)NNODES * 4;                 // [N,4]
    ushort* Wt0    = (ushort*)(er + (size_t)NNODES * 4);      // [128,128]
    ushort* Wt1    = Wt0 + 128 * 128;                         // [128,128]
    ushort* Wt2    = Wt1 + 128 * 128;                         // [32,128]

    const int T = 256;
    float* out = (float*)d_out;

    const int GATHER4_BLOCKS = (NNODES / 2 * 64) / T;         // 2 nodes/wave: 6250
    const int GATHER1_BLOCKS = (NNODES * 64) / T;             // 12500
    const int GEMM128_BLOCKS = (NNODES + 63) / 64;            // 782
    const int GEMM32_BLOCKS  = (NNODES + 127) / 128;          // 391

    // ---- single zero-init (counters + rhist + rcursor + pooled) ----
    hipMemsetAsync(counters, 0, (size_t)(8 + NRANGE + NRANGE + NGRAPHS * 32) * 4, stream);
    prep_hist_kernel<<<RH_NB, T, 0, stream>>>(W0, W1, W2, Wt0, Wt1, Wt2, edst, rhist, rowptr);
    reorder_kernel<<<RH_NB, T, 0, stream>>>(esrc, edst, rhist, rcursor, bucket);

    // ================= Layer 0 GEMM fused with CSR finalize (independent roles) ======
    csr_gemm0_kernel<<<NRANGE + GEMM128_BLOCKS, T, 0, stream>>>(
        rhist, bucket, rowptr, csr_src, x, Wt0, al0, ar0, featbf, el, er);
    gat_gather4_kernel<<<GATHER4_BLOCKS, T, 0, stream>>>(rowptr, csr_src, el, er, featbf, b0, xnext);
    bn_stats_kernel<<<BN_NB, T, 0, stream>>>(xnext, psum, psumsq, g0, beta0, scale0, shift0,
                                             &counters[0]);

    // ================= Layer 1 =================
    gemm_mfma_kernel<128, true><<<GEMM128_BLOCKS, T, 0, stream>>>(
        xnext, Wt1, scale0, shift0, al1, ar1, featbf, el, er, NNODES);
    gat_gather4_kernel<<<GATHER4_BLOCKS, T, 0, stream>>>(rowptr, csr_src, el, er, featbf, b1, xnext);
    bn_stats_kernel<<<BN_NB, T, 0, stream>>>(xnext, psum, psumsq, g1, beta1, scale1, shift1,
                                             &counters[1]);

    // ================= Layer 2 (H=1, D=32) =================
    gemm_mfma_kernel<32, true><<<GEMM32_BLOCKS, T, 0, stream>>>(
        xnext, Wt2, scale1, shift1, al2, ar2, featbf, el, er, NNODES);
    gat_gather1_kernel<<<GATHER1_BLOCKS, T, 0, stream>>>(rowptr, csr_src, el, er, featbf, b2,
                                                         gid, pooled);

    // ================= Classify =================
    classify_kernel<<<(NGRAPHS * 10 + T - 1) / T, T, 0, stream>>>(pooled, Wc, bc, out);
}